// Round 1
// baseline (550.065 us; speedup 1.0000x reference)
//
#include <hip/hip_runtime.h>
#include <math.h>

#define BB 32
#define CC 512
#define DD 4096
#define HH 128

// ---------------------------------------------------------------------------
// float4 cross-lane xor shuffle (component-wise)
// ---------------------------------------------------------------------------
__device__ __forceinline__ float4 shfl_xor_f4(float4 v, int mask) {
    float4 r;
    r.x = __shfl_xor(v.x, mask, 64);
    r.y = __shfl_xor(v.y, mask, 64);
    r.z = __shfl_xor(v.z, mask, 64);
    r.w = __shfl_xor(v.w, mask, 64);
    return r;
}

// ---------------------------------------------------------------------------
// Kernel 1: bitwise replica of np.mean(x, axis=2) fp32 — same pairwise tree
// as the verified scalar version, re-expressed with float4 loads (16 vs 64
// VMEM instructions per lane).
// Tree (per 128-float block): chunks c0..c7 of 16 floats, element-wise
//   T = ((c0+c1)+(c2+c3))+((c4+c5)+(c6+c7)),
// then element tree strides 8,4,2,1; blocks combined in-order balanced
// binary over 32 blocks. FP add is bitwise-commutative, so lanes holding
// the partner value compute identical bits.
// Lane map: bq=l>>4 (block of quad), cp=(l>>2)&3 (chunk pair), p=l&3 (f4
// position). Load A=chunk 2cp, B=chunk 2cp+1 at elems 4p..4p+3:
//   u=A+B            -> (c_{2cp}+c_{2cp+1})        level 1 (in-register)
//   u+=xor4          -> (c0+c1)+(c2+c3) | (c4+c5)+(c6+c7)   level 2
//   u+=xor8          -> full chunk tree T                      level 3
//   u+=xor2, u+=xor1 -> element strides 8,4 (r=4p+comp)
//   (u.x+u.z)+(u.y+u.w) -> element strides 2,1 -> block sum S
//   S+=xor16, S+=xor32  -> in-order pair/quad of blocks
// One wave per row; 4 rows per 256-thread block.
// ---------------------------------------------------------------------------
__global__ __launch_bounds__(256) void pool_mean_np(const float* __restrict__ x,
                                                    float* __restrict__ pooled) {
    const int wave = threadIdx.x >> 6;
    const int l = threadIdx.x & 63;
    const int row = blockIdx.x * 4 + wave;
    const float4* __restrict__ xr = (const float4*)(x + (size_t)row * DD);

    const int bq = l >> 4;        // block within quad (0..3)
    const int cp = (l >> 2) & 3;  // chunk pair (0..3)
    const int p  = l & 3;         // f4 position within chunk (0..3)

    float q8[8];
#pragma unroll
    for (int it = 0; it < 8; ++it) {
        const int blk = 4 * it + bq;
        const int ia = blk * 32 + 8 * cp + p;   // chunk 2cp, elems 4p..4p+3
        float4 A = xr[ia];
        float4 B = xr[ia + 4];                  // chunk 2cp+1, same elems
        float4 u;
        u.x = A.x + B.x; u.y = A.y + B.y; u.z = A.z + B.z; u.w = A.w + B.w;
        float4 t;
        t = shfl_xor_f4(u, 4); u.x += t.x; u.y += t.y; u.z += t.z; u.w += t.w;
        t = shfl_xor_f4(u, 8); u.x += t.x; u.y += t.y; u.z += t.z; u.w += t.w;
        // element tree: stride 8 -> lane xor2, stride 4 -> lane xor1
        t = shfl_xor_f4(u, 2); u.x += t.x; u.y += t.y; u.z += t.z; u.w += t.w;
        t = shfl_xor_f4(u, 1); u.x += t.x; u.y += t.y; u.z += t.z; u.w += t.w;
        float h0 = u.x + u.z;                   // stride 2
        float h1 = u.y + u.w;
        float S = h0 + h1;                      // stride 1 -> block sum B_blk
        S += __shfl_xor(S, 16, 64);             // (B_{4it}+B_{4it+1}) etc.
        S += __shfl_xor(S, 32, 64);             // quad sum Q_it
        q8[it] = S;
    }
    float t01 = q8[0] + q8[1], t23 = q8[2] + q8[3];
    float t45 = q8[4] + q8[5], t67 = q8[6] + q8[7];
    float tot = (t01 + t23) + (t45 + t67);
    if (l == 0) pooled[row] = tot / 4096.0f;    // /2^12: exact
}

// ---------------------------------------------------------------------------
// Kernel 2: fp32 MLP, bit-identical fmaf chains, now fed from LDS-staged
// weight panels (coalesced float4 global loads) instead of per-lane strided
// global walks.
//   W1 panel: [128 rows][64 cols], element swizzle k^(r&31)  -> 2-way (free)
//   W2 panel: [512 rows][17 pad],   pad-17                   -> 2-way (free)
// Layer 1 (K=512): u = fmaf chain k=0..255, v = 256..511, acc=u+v, +b1,
// LeakyReLU(0.01). Layer 2 (K=128): single chain, +b2, sigmoid via
// correctly-rounded fp32 exp (double). Stable descending rank-count.
// ---------------------------------------------------------------------------
__global__ __launch_bounds__(512) void mlp_sort_np(
    const float* __restrict__ pooled,
    const float* __restrict__ W1, const float* __restrict__ b1,
    const float* __restrict__ W2, const float* __restrict__ b2,
    int* __restrict__ order) {
    const int b = blockIdx.x;
    const int t = threadIdx.x;

    __shared__ float p[CC];
    __shared__ float h[HH];
    __shared__ float s[CC];
    __shared__ float wbuf[8704];  // max(W1 panel 8192, W2 panel 512*17=8704)

    p[t] = pooled[b * CC + t];

    // ---- Layer 1: panels of 64 columns; u over panels 0..3, v over 4..7
    float u = 0.0f, v = 0.0f;
    const float4* __restrict__ W1v = (const float4*)W1;
#pragma unroll 1
    for (int pi = 0; pi < 8; ++pi) {
        const int k0 = pi * 64;
        __syncthreads();                        // previous panel consumed
#pragma unroll
        for (int si = 0; si < 4; ++si) {        // 2048 f4 = 4 per thread
            const int f = t + 512 * si;
            const int r = f >> 4;               // row 0..127
            const int j = f & 15;               // f4 within row-panel
            float4 val = W1v[r * 128 + (k0 >> 2) + j];
            const int base = r << 6;
            const int sw = r & 31;
            wbuf[base + ((4 * j + 0) ^ sw)] = val.x;
            wbuf[base + ((4 * j + 1) ^ sw)] = val.y;
            wbuf[base + ((4 * j + 2) ^ sw)] = val.z;
            wbuf[base + ((4 * j + 3) ^ sw)] = val.w;
        }
        __syncthreads();
        if (t < HH) {
            const int base = t << 6;
            const int sw = t & 31;
            float acc = (pi < 4) ? u : v;
            for (int kk = 0; kk < 64; ++kk)
                acc = fmaf(p[k0 + kk], wbuf[base + (kk ^ sw)], acc);
            if (pi < 4) u = acc; else v = acc;
        }
    }
    if (t < HH) {
        float acc = u + v;                      // K-panel combine (256+256)
        float hv = acc + b1[t];
        h[t] = (hv >= 0.0f) ? hv : 0.01f * hv;  // LeakyReLU(0.01)
    }

    // ---- Layer 2: panels of 16 columns, pad-17 LDS rows
    float acc2 = 0.0f;
    const float4* __restrict__ W2v = (const float4*)W2;
#pragma unroll 1
    for (int pi = 0; pi < 8; ++pi) {
        const int k0 = pi * 16;
        __syncthreads();                        // orders h-write & wbuf reuse
#pragma unroll
        for (int si = 0; si < 4; ++si) {        // 2048 f4 = 4 per thread
            const int f = t + 512 * si;
            const int r = f >> 2;               // row 0..511
            const int j = f & 3;                // f4 within row-panel
            float4 val = W2v[r * 32 + (k0 >> 2) + j];
            float* dst = &wbuf[r * 17 + 4 * j];
            dst[0] = val.x; dst[1] = val.y; dst[2] = val.z; dst[3] = val.w;
        }
        __syncthreads();
        const float* __restrict__ wrow = &wbuf[t * 17];
#pragma unroll
        for (int kk = 0; kk < 16; ++kk)
            acc2 = fmaf(h[k0 + kk], wrow[kk], acc2);
    }
    {
        float z = acc2 + b2[t];
        float e = (float)exp(-(double)z);       // correctly-rounded fp32 exp
        s[t] = 1.0f / (1.0f + e);
    }
    __syncthreads();

    const float mine = s[t];
    int rank = 0;
    for (int j = 0; j < CC; ++j) {
        float vv = s[j];
        rank += (vv > mine) || (vv == mine && j < t);
    }
    order[b * CC + rank] = t;
}

// ---------------------------------------------------------------------------
// Kernel 3: out[b,r,:] = x[b,r,:] + x[b, order[b,r], :]. float4 everywhere.
// ---------------------------------------------------------------------------
__global__ __launch_bounds__(256) void gather_add_kernel(
    const float* __restrict__ x, const int* __restrict__ order,
    float* __restrict__ out) {
    const int row = blockIdx.x;  // b*CC + r
    const int b = row >> 9;      // CC == 512
    const int src = order[row];
    const float4* __restrict__ xi = (const float4*)(x + (size_t)row * DD);
    const float4* __restrict__ xs =
        (const float4*)(x + ((size_t)(b * CC + src)) * DD);
    float4* __restrict__ o = (float4*)(out + (size_t)row * DD);
    const int t = threadIdx.x;
#pragma unroll
    for (int i = 0; i < 4; ++i) {
        float4 a = xi[t + i * 256];
        float4 g = xs[t + i * 256];
        o[t + i * 256] = make_float4(a.x + g.x, a.y + g.y, a.z + g.z, a.w + g.w);
    }
}

extern "C" void kernel_launch(void* const* d_in, const int* in_sizes, int n_in,
                              void* d_out, int out_size, void* d_ws,
                              size_t ws_size, hipStream_t stream) {
    const float* x  = (const float*)d_in[0];
    const float* W1 = (const float*)d_in[1];
    const float* b1 = (const float*)d_in[2];
    const float* W2 = (const float*)d_in[3];
    const float* b2 = (const float*)d_in[4];
    float* out = (float*)d_out;

    // workspace: [pooled: 16384 f32][order: 16384 i32]
    float* pooled = (float*)d_ws;
    int* order = (int*)((char*)d_ws + (size_t)BB * CC * sizeof(float));

    pool_mean_np<<<BB * CC / 4, 256, 0, stream>>>(x, pooled);
    mlp_sort_np<<<BB, 512, 0, stream>>>(pooled, W1, b1, W2, b2, order);
    gather_add_kernel<<<BB * CC, 256, 0, stream>>>(x, order, out);
}

// Round 3
// 539.791 us; speedup vs baseline: 1.0190x; 1.0190x over previous
//
#include <hip/hip_runtime.h>
#include <math.h>

#define BB 32
#define CC 512
#define DD 4096
#define HH 128

typedef float f4_native __attribute__((ext_vector_type(4)));

// ---------------------------------------------------------------------------
// float4 cross-lane xor shuffle (component-wise)
// ---------------------------------------------------------------------------
__device__ __forceinline__ float4 shfl_xor_f4(float4 v, int mask) {
    float4 r;
    r.x = __shfl_xor(v.x, mask, 64);
    r.y = __shfl_xor(v.y, mask, 64);
    r.z = __shfl_xor(v.z, mask, 64);
    r.w = __shfl_xor(v.w, mask, 64);
    return r;
}

// ---------------------------------------------------------------------------
// Kernel 1: bitwise replica of np.mean(x, axis=2) fp32 — numpy pairwise-sum
// tree, float4 loads. Verified bit-exact (absmax 0.0 two rounds running).
// Side effect relied on by kernel 3: streams all 256 MiB of x through the
// memory-side Infinity Cache (L3 == 256 MiB) so x is L3-resident for gather.
// ---------------------------------------------------------------------------
__global__ __launch_bounds__(256) void pool_mean_np(const float* __restrict__ x,
                                                    float* __restrict__ pooled) {
    const int wave = threadIdx.x >> 6;
    const int l = threadIdx.x & 63;
    const int row = blockIdx.x * 4 + wave;
    const float4* __restrict__ xr = (const float4*)(x + (size_t)row * DD);

    const int bq = l >> 4;        // block within quad (0..3)
    const int cp = (l >> 2) & 3;  // chunk pair (0..3)
    const int p  = l & 3;         // f4 position within chunk (0..3)

    float q8[8];
#pragma unroll
    for (int it = 0; it < 8; ++it) {
        const int blk = 4 * it + bq;
        const int ia = blk * 32 + 8 * cp + p;   // chunk 2cp, elems 4p..4p+3
        float4 A = xr[ia];
        float4 B = xr[ia + 4];                  // chunk 2cp+1, same elems
        float4 u;
        u.x = A.x + B.x; u.y = A.y + B.y; u.z = A.z + B.z; u.w = A.w + B.w;
        float4 t;
        t = shfl_xor_f4(u, 4); u.x += t.x; u.y += t.y; u.z += t.z; u.w += t.w;
        t = shfl_xor_f4(u, 8); u.x += t.x; u.y += t.y; u.z += t.z; u.w += t.w;
        t = shfl_xor_f4(u, 2); u.x += t.x; u.y += t.y; u.z += t.z; u.w += t.w;
        t = shfl_xor_f4(u, 1); u.x += t.x; u.y += t.y; u.z += t.z; u.w += t.w;
        float h0 = u.x + u.z;                   // stride 2
        float h1 = u.y + u.w;
        float S = h0 + h1;                      // stride 1 -> block sum
        S += __shfl_xor(S, 16, 64);
        S += __shfl_xor(S, 32, 64);
        q8[it] = S;
    }
    float t01 = q8[0] + q8[1], t23 = q8[2] + q8[3];
    float t45 = q8[4] + q8[5], t67 = q8[6] + q8[7];
    float tot = (t01 + t23) + (t45 + t67);
    if (l == 0) pooled[row] = tot / 4096.0f;    // /2^12: exact
}

// ---------------------------------------------------------------------------
// Kernel 2: fp32 MLP, bit-identical fmaf chains from LDS-staged weight
// panels. Verified bit-exact. ~8 µs — not a bottleneck.
// ---------------------------------------------------------------------------
__global__ __launch_bounds__(512) void mlp_sort_np(
    const float* __restrict__ pooled,
    const float* __restrict__ W1, const float* __restrict__ b1,
    const float* __restrict__ W2, const float* __restrict__ b2,
    int* __restrict__ order) {
    const int b = blockIdx.x;
    const int t = threadIdx.x;

    __shared__ float p[CC];
    __shared__ float h[HH];
    __shared__ float s[CC];
    __shared__ float wbuf[8704];  // max(W1 panel 8192, W2 panel 512*17=8704)

    p[t] = pooled[b * CC + t];

    // ---- Layer 1: panels of 64 columns; u over panels 0..3, v over 4..7
    float u = 0.0f, v = 0.0f;
    const float4* __restrict__ W1v = (const float4*)W1;
#pragma unroll 1
    for (int pi = 0; pi < 8; ++pi) {
        const int k0 = pi * 64;
        __syncthreads();                        // previous panel consumed
#pragma unroll
        for (int si = 0; si < 4; ++si) {        // 2048 f4 = 4 per thread
            const int f = t + 512 * si;
            const int r = f >> 4;               // row 0..127
            const int j = f & 15;               // f4 within row-panel
            float4 val = W1v[r * 128 + (k0 >> 2) + j];
            const int base = r << 6;
            const int sw = r & 31;
            wbuf[base + ((4 * j + 0) ^ sw)] = val.x;
            wbuf[base + ((4 * j + 1) ^ sw)] = val.y;
            wbuf[base + ((4 * j + 2) ^ sw)] = val.z;
            wbuf[base + ((4 * j + 3) ^ sw)] = val.w;
        }
        __syncthreads();
        if (t < HH) {
            const int base = t << 6;
            const int sw = t & 31;
            float acc = (pi < 4) ? u : v;
            for (int kk = 0; kk < 64; ++kk)
                acc = fmaf(p[k0 + kk], wbuf[base + (kk ^ sw)], acc);
            if (pi < 4) u = acc; else v = acc;
        }
    }
    if (t < HH) {
        float acc = u + v;                      // K-panel combine (256+256)
        float hv = acc + b1[t];
        h[t] = (hv >= 0.0f) ? hv : 0.01f * hv;  // LeakyReLU(0.01)
    }

    // ---- Layer 2: panels of 16 columns, pad-17 LDS rows
    float acc2 = 0.0f;
    const float4* __restrict__ W2v = (const float4*)W2;
#pragma unroll 1
    for (int pi = 0; pi < 8; ++pi) {
        const int k0 = pi * 16;
        __syncthreads();                        // orders h-write & wbuf reuse
#pragma unroll
        for (int si = 0; si < 4; ++si) {        // 2048 f4 = 4 per thread
            const int f = t + 512 * si;
            const int r = f >> 2;               // row 0..511
            const int j = f & 3;                // f4 within row-panel
            float4 val = W2v[r * 32 + (k0 >> 2) + j];
            float* dst = &wbuf[r * 17 + 4 * j];
            dst[0] = val.x; dst[1] = val.y; dst[2] = val.z; dst[3] = val.w;
        }
        __syncthreads();
        const float* __restrict__ wrow = &wbuf[t * 17];
#pragma unroll
        for (int kk = 0; kk < 16; ++kk)
            acc2 = fmaf(h[k0 + kk], wrow[kk], acc2);
    }
    {
        float z = acc2 + b2[t];
        float e = (float)exp(-(double)z);       // correctly-rounded fp32 exp
        s[t] = 1.0f / (1.0f + e);
    }
    __syncthreads();

    const float mine = s[t];
    int rank = 0;
    for (int j = 0; j < CC; ++j) {
        float vv = s[j];
        rank += (vv > mine) || (vv == mine && j < t);
    }
    order[b * CC + rank] = t;
}

// ---------------------------------------------------------------------------
// Kernel 3: out[b,r,:] = x[b,r,:] + x[b, order[b,r], :]. float4 loads,
// nontemporal vector stores for out (written once, never read). Regular
// stores allocate in the memory-side Infinity Cache and evict the 256 MiB
// x working set (exactly L3-sized) while gather is still reading it twice;
// NT stores keep x L3-resident. Store uses a native clang ext_vector_type
// (the builtin rejects HIP's float4 struct). Arithmetic unchanged ->
// bit-exact.
// ---------------------------------------------------------------------------
__global__ __launch_bounds__(256) void gather_add_kernel(
    const float* __restrict__ x, const int* __restrict__ order,
    float* __restrict__ out) {
    const int row = blockIdx.x;  // b*CC + r
    const int b = row >> 9;      // CC == 512
    const int src = order[row];
    const float4* __restrict__ xi = (const float4*)(x + (size_t)row * DD);
    const float4* __restrict__ xs =
        (const float4*)(x + ((size_t)(b * CC + src)) * DD);
    f4_native* __restrict__ o = (f4_native*)(out + (size_t)row * DD);
    const int t = threadIdx.x;
#pragma unroll
    for (int i = 0; i < 4; ++i) {
        float4 a = xi[t + i * 256];
        float4 g = xs[t + i * 256];
        f4_native r;
        r.x = a.x + g.x; r.y = a.y + g.y; r.z = a.z + g.z; r.w = a.w + g.w;
        __builtin_nontemporal_store(r, &o[t + i * 256]);
    }
}

extern "C" void kernel_launch(void* const* d_in, const int* in_sizes, int n_in,
                              void* d_out, int out_size, void* d_ws,
                              size_t ws_size, hipStream_t stream) {
    const float* x  = (const float*)d_in[0];
    const float* W1 = (const float*)d_in[1];
    const float* b1 = (const float*)d_in[2];
    const float* W2 = (const float*)d_in[3];
    const float* b2 = (const float*)d_in[4];
    float* out = (float*)d_out;

    // workspace: [pooled: 16384 f32][order: 16384 i32]
    float* pooled = (float*)d_ws;
    int* order = (int*)((char*)d_ws + (size_t)BB * CC * sizeof(float));

    pool_mean_np<<<BB * CC / 4, 256, 0, stream>>>(x, pooled);
    mlp_sort_np<<<BB, 512, 0, stream>>>(pooled, W1, b1, W2, b2, order);
    gather_add_kernel<<<BB * CC, 256, 0, stream>>>(x, order, out);
}